// Round 2
// baseline (317.257 us; speedup 1.0000x reference)
//
#include <hip/hip_runtime.h>

typedef unsigned short u16;
typedef __attribute__((ext_vector_type(8))) short short8;
typedef __attribute__((ext_vector_type(4))) unsigned short u16x4;
typedef __attribute__((ext_vector_type(4))) float f32x4;

#define N_TOKENS 32768
#define EMBED 512
#define NCLS 16
#define NBATCH 8
#define NHEAD 8
#define DHEAD 64

__device__ __forceinline__ u16 f2bf(float f) {
  unsigned u = __float_as_uint(f);
  u += 0x7fffu + ((u >> 16) & 1u);   // RNE
  return (u16)(u >> 16);
}

// ---------------- fp32 -> bf16 converter (4 elems/thread) ----------------
__global__ __launch_bounds__(256) void cvt_bf16(const float4* __restrict__ in,
                                                u16x4* __restrict__ out, int n4) {
  int i = blockIdx.x * blockDim.x + threadIdx.x;
  if (i >= n4) return;
  float4 v = in[i];
  u16x4 o;
  o[0] = f2bf(v.x); o[1] = f2bf(v.y); o[2] = f2bf(v.z); o[3] = f2bf(v.w);
  out[i] = o;
}

// ---------------- K/V projection ----------------
__global__ __launch_bounds__(256) void kvproj_kernel(
    const float* __restrict__ key, const float* __restrict__ val,
    const float* __restrict__ Wk, const float* __restrict__ bk,
    const float* __restrict__ Wv, const float* __restrict__ bv,
    float* __restrict__ kproj, float* __restrict__ vproj) {
  int t = blockIdx.x * blockDim.x + threadIdx.x;   // [0, 2*65536)
  const bool isV = t >= 65536;                      // wave-uniform
  int idx = t & 65535;
  int f = idx & 511;
  int bl = idx >> 9;
  int l = bl & 15;
  int b = bl >> 4;
  const float* src = isV ? val : key;
  const float* W = isV ? Wv : Wk;
  const float* bias = isV ? bv : bk;
  const float4* s4 = (const float4*)(src + (size_t)l * (NBATCH * EMBED) + (size_t)b * EMBED);
  const float4* w4 = (const float4*)(W + (size_t)f * EMBED);
  float acc = 0.f;
#pragma unroll 8
  for (int e = 0; e < EMBED / 4; e++) {
    float4 a = s4[e], w = w4[e];
    acc += a.x * w.x + a.y * w.y + a.z * w.z + a.w * w.w;
  }
  acc += bias[f];
  if (!isV) {
    kproj[((size_t)(b * EMBED + f)) * NCLS + l] = acc;           // [b][h][d][l]
  } else {
    int h = f >> 6, d = f & 63;
    vproj[(size_t)b * 8192 + (size_t)h * 1024 + l * 64 + d] = acc;  // [b][h][l][d]
  }
}

// ---------------- Kq[b][hl][e] = sum_d Wq[h*64+d][e] * kproj[b,h,d,l]  (bf16) ----
__global__ __launch_bounds__(256) void build_kq(const float* __restrict__ kproj,
                                                const float* __restrict__ Wq,
                                                u16* __restrict__ Kqb) {
  int t = blockIdx.x * 256 + threadIdx.x;   // 8*128*512
  int e = t & 511;
  int hl = (t >> 9) & 127;
  int b = t >> 16;
  int h = hl >> 4, l = hl & 15;
  const float* kp = kproj + (size_t)b * 8192 + h * 1024 + l;
  const float* wq = Wq + (size_t)(h * 64) * 512 + e;
  float acc = 0.f;
#pragma unroll 16
  for (int d = 0; d < 64; d++) acc += kp[d * 16] * wq[d * 512];
  Kqb[t] = f2bf(acc);
}

// ---------------- sb[b][hl] = sum_d bq[h*64+d] * kproj[b,h,d,l] ----------------
__global__ void build_sb(const float* __restrict__ kproj, const float* __restrict__ bq,
                         float* __restrict__ sb) {
  int t = blockIdx.x * 256 + threadIdx.x;   // 1024
  int hl = t & 127, b = t >> 7;
  int h = hl >> 4, l = hl & 15;
  const float* kp = kproj + (size_t)b * 8192 + h * 1024 + l;
  const float* q = bq + h * 64;
  float acc = 0.f;
#pragma unroll
  for (int d = 0; d < 64; d++) acc += q[d] * kp[d * 16];
  sb[t] = acc;
}

// ---------------- WoV[b][f][hl] = sum_d vproj[b,h,l,d] * Wo[f][h*64+d]  (bf16) ----
__global__ __launch_bounds__(256) void build_wov(const float* __restrict__ vproj,
                                                 const float* __restrict__ Wo,
                                                 u16* __restrict__ WoVb) {
  int t = blockIdx.x * 256 + threadIdx.x;   // 8*512*128
  int hl = t & 127;
  int f = (t >> 7) & 511;
  int b = t >> 16;
  int h = hl >> 4, l = hl & 15;
  const float* vp = vproj + (size_t)b * 8192 + h * 1024 + l * 64;
  const float* wo = Wo + (size_t)f * 512 + h * 64;
  float acc = 0.f;
#pragma unroll 16
  for (int d = 0; d < 64; d++) acc += vp[d] * wo[d];
  WoVb[t] = f2bf(acc);
}

// ---------------- fused: scores GEMM + softmax + out GEMM ----------------
// v2: residency-first design. 64-token tiles (grid 512), 4 waves/block,
// LDS = 16 KB (swizzled P bounce only) + VGPR<=168 via launch_bounds(256,3)
// -> 3 blocks/CU, all 512 blocks resident, stragglers overlap.
// Phase 1: C[64,128] = qbf[64,512] x Kq[bb]^T, A/B fragments loaded DIRECTLY
// from global (Kq 128KB L2-resident, qbf L3-resident), no LDS, no barriers.
// Softmax per head's 16 l-cols via shfl; P -> 16KB XOR-swizzled LDS.
// Phase 2: out[64,512] = P x WoV[bb]^T, B fragments direct from L2, P frags
// from LDS. Predicated store per row's batch (bidx sorted).
__global__ __launch_bounds__(256, 3) void fused_attn(
    const u16* __restrict__ A, const u16* __restrict__ Kqb,
    const u16* __restrict__ WoVb, const float* __restrict__ sb,
    const float* __restrict__ bo, const int* __restrict__ bidx,
    float* __restrict__ out) {
  __shared__ __align__(16) u16 Ps[64 * 128];   // 16 KB, XOR-swizzled chunks
  const int tid = threadIdx.x;
  const int lane = tid & 63;
  const int wave = tid >> 6;
  const int wr = (wave >> 1) * 32;   // phase-1 row base (within tile)
  const int wc = (wave & 1) * 64;    // phase-1 col base (hl)
  const int quad = lane >> 4;
  const int l16 = lane & 15;
  const int m0 = blockIdx.x * 64;
  const int bFirst = bidx[m0];
  const int bLast = bidx[m0 + 63];

  // per-row batch for predicated stores (phase 2: wave covers all 64 rows)
  int rowb[4][4];
#pragma unroll
  for (int mi = 0; mi < 4; mi++)
#pragma unroll
    for (int r = 0; r < 4; r++) rowb[mi][r] = bidx[m0 + mi * 16 + quad * 4 + r];

  // phase-1 A fragment base pointers (row-unique per mi, k-slice quad*8)
  const u16* pA[2];
#pragma unroll
  for (int mi = 0; mi < 2; mi++)
    pA[mi] = A + (size_t)(m0 + wr + mi * 16 + l16) * 512 + quad * 8;

  for (int bb = bFirst; bb <= bLast; bb++) {
    // ---- phase 1: scores, fragments direct from global ----
    const u16* Bq = Kqb + (size_t)bb * 65536;
    const u16* pB[4];
#pragma unroll
    for (int ni = 0; ni < 4; ni++)
      pB[ni] = Bq + (size_t)(wc + ni * 16 + l16) * 512 + quad * 8;

    f32x4 acc1[2][4];
#pragma unroll
    for (int i = 0; i < 2; i++)
#pragma unroll
      for (int j = 0; j < 4; j++) acc1[i][j] = (f32x4){0.f, 0.f, 0.f, 0.f};

#pragma unroll 4
    for (int t = 0; t < 16; t++) {
      short8 af[2], bfr[4];
#pragma unroll
      for (int mi = 0; mi < 2; mi++) af[mi] = *(const short8*)(pA[mi] + t * 32);
#pragma unroll
      for (int ni = 0; ni < 4; ni++) bfr[ni] = *(const short8*)(pB[ni] + t * 32);
#pragma unroll
      for (int mi = 0; mi < 2; mi++)
#pragma unroll
        for (int ni = 0; ni < 4; ni++)
          acc1[mi][ni] = __builtin_amdgcn_mfma_f32_16x16x32_bf16(af[mi], bfr[ni], acc1[mi][ni], 0, 0, 0);
    }

    // ---- softmax over each head's 16 l-cols (16-lane shfl), P -> LDS ----
    float sbv[4];
#pragma unroll
    for (int ni = 0; ni < 4; ni++) sbv[ni] = sb[bb * 128 + wc + ni * 16 + l16];
#pragma unroll
    for (int mi = 0; mi < 2; mi++) {
#pragma unroll
      for (int r = 0; r < 4; r++) {
        const int row = wr + mi * 16 + quad * 4 + r;   // 0..63
#pragma unroll
        for (int ni = 0; ni < 4; ni++) {
          float v = acc1[mi][ni][r] + sbv[ni];
          float mx = v;
          mx = fmaxf(mx, __shfl_xor(mx, 1));
          mx = fmaxf(mx, __shfl_xor(mx, 2));
          mx = fmaxf(mx, __shfl_xor(mx, 4));
          mx = fmaxf(mx, __shfl_xor(mx, 8));
          float ev = __expf((v - mx) * 0.125f);   // scale = D^-0.5
          float s = ev;
          s += __shfl_xor(s, 1);
          s += __shfl_xor(s, 2);
          s += __shfl_xor(s, 4);
          s += __shfl_xor(s, 8);
          const int col = wc + ni * 16 + l16;
          Ps[row * 128 + ((((col >> 3) ^ (row & 7)) << 3)) + (col & 7)] = f2bf(ev / s);
        }
      }
    }
    __syncthreads();   // all P stripes visible

    // ---- phase 2: out[64,512] = P x WoV[bb]^T; wave owns 128 f-cols ----
    const int fb = wave * 128;
    const u16* Wv = WoVb + (size_t)bb * 65536;
#pragma unroll
    for (int h2 = 0; h2 < 2; h2++) {
      const int f0 = fb + h2 * 64;
      f32x4 acc2[4][4];
#pragma unroll
      for (int i = 0; i < 4; i++)
#pragma unroll
        for (int j = 0; j < 4; j++) acc2[i][j] = (f32x4){0.f, 0.f, 0.f, 0.f};
#pragma unroll
      for (int kk = 0; kk < 4; kk++) {
        short8 paf[4], bf2[4];
#pragma unroll
        for (int mi = 0; mi < 4; mi++) {
          const int row = mi * 16 + l16;
          paf[mi] = *(const short8*)&Ps[row * 128 + (((kk * 4 + quad) ^ (row & 7)) << 3)];
        }
#pragma unroll
        for (int ni = 0; ni < 4; ni++) {
          const int fr = f0 + ni * 16 + l16;
          bf2[ni] = *(const short8*)(Wv + (size_t)fr * 128 + kk * 32 + quad * 8);
        }
#pragma unroll
        for (int mi = 0; mi < 4; mi++)
#pragma unroll
          for (int ni = 0; ni < 4; ni++)
            acc2[mi][ni] = __builtin_amdgcn_mfma_f32_16x16x32_bf16(paf[mi], bf2[ni], acc2[mi][ni], 0, 0, 0);
      }
      float bov[4];
#pragma unroll
      for (int ni = 0; ni < 4; ni++) bov[ni] = bo[f0 + ni * 16 + l16];
#pragma unroll
      for (int mi = 0; mi < 4; mi++)
#pragma unroll
        for (int r = 0; r < 4; r++) {
          if (rowb[mi][r] == bb) {
            const size_t row = m0 + mi * 16 + quad * 4 + r;
#pragma unroll
            for (int ni = 0; ni < 4; ni++)
              out[row * 512 + f0 + ni * 16 + l16] = acc2[mi][ni][r] + bov[ni];
          }
        }
    }
    __syncthreads();   // protect Ps before next bb overwrites
  }
}

extern "C" void kernel_launch(void* const* d_in, const int* in_sizes, int n_in,
                              void* d_out, int out_size, void* d_ws, size_t ws_size,
                              hipStream_t stream) {
  const float* query = (const float*)d_in[0];
  const float* keyt = (const float*)d_in[1];
  const float* valt = (const float*)d_in[2];
  const int* bidx = (const int*)d_in[3];
  // d_in[4] = batch_size (scalar, fixed = 8)
  const float* Wq = (const float*)d_in[5];
  const float* bq = (const float*)d_in[6];
  const float* Wk = (const float*)d_in[7];
  const float* bk = (const float*)d_in[8];
  const float* Wv = (const float*)d_in[9];
  const float* bv = (const float*)d_in[10];
  const float* Wo = (const float*)d_in[11];
  const float* bo = (const float*)d_in[12];
  float* out = (float*)d_out;

  // workspace layout (bytes)
  unsigned char* w = (unsigned char*)d_ws;
  u16* qbf = (u16*)(w);                       // 33,554,432: query bf16 [N,E]
  float* kproj = (float*)(w + 41943040ull);   //    262,144: [B,H,D,L]
  float* vproj = (float*)(w + 42205184ull);   //    262,144: [B,H,L,D]
  u16* Kqb = (u16*)(w + 42467328ull);         //  1,048,576: [B,128,512] bf16
  u16* WoVb = (u16*)(w + 43515904ull);        //  1,048,576: [B,512,128] bf16
  float* sb = (float*)(w + 44564480ull);      //      4,096: [B,128]

  // 1) query -> bf16
  cvt_bf16<<<N_TOKENS * EMBED / 4 / 256, 256, 0, stream>>>(
      (const float4*)query, (u16x4*)qbf, N_TOKENS * EMBED / 4);

  // 2) K/V projections (fp32, tiny)
  kvproj_kernel<<<512, 256, 0, stream>>>(keyt, valt, Wk, bk, Wv, bv, kproj, vproj);

  // 3) fold Wq through k, Wo through v
  build_kq<<<2048, 256, 0, stream>>>(kproj, Wq, Kqb);
  build_sb<<<4, 256, 0, stream>>>(kproj, bq, sb);
  build_wov<<<2048, 256, 0, stream>>>(vproj, Wo, WoVb);

  // 4) fused scores + softmax + out
  fused_attn<<<N_TOKENS / 64, 256, 0, stream>>>(qbf, Kqb, WoVb, sb, bo, bidx, out);
}

// Round 3
// 295.710 us; speedup vs baseline: 1.0729x; 1.0729x over previous
//
#include <hip/hip_runtime.h>

typedef unsigned short u16;
typedef __attribute__((ext_vector_type(8))) short short8;
typedef __attribute__((ext_vector_type(4))) unsigned short u16x4;
typedef __attribute__((ext_vector_type(4))) float f32x4;

#define N_TOKENS 32768
#define EMBED 512
#define NCLS 16
#define NBATCH 8
#define NHEAD 8
#define DHEAD 64

__device__ __forceinline__ u16 f2bf(float f) {
  unsigned u = __float_as_uint(f);
  u += 0x7fffu + ((u >> 16) & 1u);   // RNE
  return (u16)(u >> 16);
}

// ---------------- K/V projection ----------------
__global__ __launch_bounds__(256) void kvproj_kernel(
    const float* __restrict__ key, const float* __restrict__ val,
    const float* __restrict__ Wk, const float* __restrict__ bk,
    const float* __restrict__ Wv, const float* __restrict__ bv,
    float* __restrict__ kproj, float* __restrict__ vproj) {
  int t = blockIdx.x * blockDim.x + threadIdx.x;   // [0, 2*65536)
  const bool isV = t >= 65536;                      // wave-uniform
  int idx = t & 65535;
  int f = idx & 511;
  int bl = idx >> 9;
  int l = bl & 15;
  int b = bl >> 4;
  const float* src = isV ? val : key;
  const float* W = isV ? Wv : Wk;
  const float* bias = isV ? bv : bk;
  const float4* s4 = (const float4*)(src + (size_t)l * (NBATCH * EMBED) + (size_t)b * EMBED);
  const float4* w4 = (const float4*)(W + (size_t)f * EMBED);
  float acc = 0.f;
#pragma unroll 8
  for (int e = 0; e < EMBED / 4; e++) {
    float4 a = s4[e], w = w4[e];
    acc += a.x * w.x + a.y * w.y + a.z * w.z + a.w * w.w;
  }
  acc += bias[f];
  if (!isV) {
    kproj[((size_t)(b * EMBED + f)) * NCLS + l] = acc;           // [b][h][d][l]
  } else {
    int h = f >> 6, d = f & 63;
    vproj[(size_t)b * 8192 + (size_t)h * 1024 + l * 64 + d] = acc;  // [b][h][l][d]
  }
}

// ---------------- Kq[b][hl][e] = sum_d Wq[h*64+d][e] * kproj[b,h,d,l]  (bf16) ----
__global__ __launch_bounds__(256) void build_kq(const float* __restrict__ kproj,
                                                const float* __restrict__ Wq,
                                                u16* __restrict__ Kqb) {
  int t = blockIdx.x * 256 + threadIdx.x;   // 8*128*512
  int e = t & 511;
  int hl = (t >> 9) & 127;
  int b = t >> 16;
  int h = hl >> 4, l = hl & 15;
  const float* kp = kproj + (size_t)b * 8192 + h * 1024 + l;
  const float* wq = Wq + (size_t)(h * 64) * 512 + e;
  float acc = 0.f;
#pragma unroll 16
  for (int d = 0; d < 64; d++) acc += kp[d * 16] * wq[d * 512];
  Kqb[t] = f2bf(acc);
}

// ---------------- sb[b][hl] = sum_d bq[h*64+d] * kproj[b,h,d,l] ----------------
__global__ void build_sb(const float* __restrict__ kproj, const float* __restrict__ bq,
                         float* __restrict__ sb) {
  int t = blockIdx.x * 256 + threadIdx.x;   // 1024
  int hl = t & 127, b = t >> 7;
  int h = hl >> 4, l = hl & 15;
  const float* kp = kproj + (size_t)b * 8192 + h * 1024 + l;
  const float* q = bq + h * 64;
  float acc = 0.f;
#pragma unroll
  for (int d = 0; d < 64; d++) acc += q[d] * kp[d * 16];
  sb[t] = acc;
}

// ---------------- WoV[b][f][hl] = sum_d vproj[b,h,l,d] * Wo[f][h*64+d]  (bf16) ----
__global__ __launch_bounds__(256) void build_wov(const float* __restrict__ vproj,
                                                 const float* __restrict__ Wo,
                                                 u16* __restrict__ WoVb) {
  int t = blockIdx.x * 256 + threadIdx.x;   // 8*512*128
  int hl = t & 127;
  int f = (t >> 7) & 511;
  int b = t >> 16;
  int h = hl >> 4, l = hl & 15;
  const float* vp = vproj + (size_t)b * 8192 + h * 1024 + l * 64;
  const float* wo = Wo + (size_t)f * 512 + h * 64;
  float acc = 0.f;
#pragma unroll 16
  for (int d = 0; d < 64; d++) acc += vp[d] * wo[d];
  WoVb[t] = f2bf(acc);
}

// ---------------- fused: fp32-query scores GEMM + softmax + out GEMM ----------------
// v3: 32-token tiles, grid 1024, 4 waves/block, LDS = 8 KB (P only),
// launch_bounds(256,4) -> 4 blocks/CU, 16 waves/CU. Conversion fp32->bf16 fused
// into A-fragment loads (cvt kernel eliminated). All 4 waves share the 32 rows;
// phase 1: wave owns 32 hl-cols (wc = wave*32, ni 0..1). Panels direct from L2.
// Phase 2: wave owns 128 f-cols; P frags from swizzled LDS. Out stores
// NONTEMPORAL (no L2 allocate) to kill the RMW write amplification seen in v2.
__global__ __launch_bounds__(256, 4) void fused_attn(
    const float* __restrict__ query, const u16* __restrict__ Kqb,
    const u16* __restrict__ WoVb, const float* __restrict__ sb,
    const float* __restrict__ bo, const int* __restrict__ bidx,
    float* __restrict__ out) {
  __shared__ __align__(16) u16 Ps[32 * 128];   // 8 KB, XOR-swizzled chunks
  const int tid = threadIdx.x;
  const int lane = tid & 63;
  const int wave = tid >> 6;
  const int wc = wave * 32;          // phase-1 col base (hl)
  const int quad = lane >> 4;
  const int l16 = lane & 15;
  const int m0 = blockIdx.x * 32;
  const int bFirst = bidx[m0];
  const int bLast = bidx[m0 + 31];

  // per-row batch for predicated stores (rows 0..31: mi*16 + quad*4 + r)
  int rowb[2][4];
#pragma unroll
  for (int mi = 0; mi < 2; mi++)
#pragma unroll
    for (int r = 0; r < 4; r++) rowb[mi][r] = bidx[m0 + mi * 16 + quad * 4 + r];

  // phase-1 A fragment base pointers (fp32 query; row mi*16+l16, k-slice quad*8)
  const float* pA[2];
#pragma unroll
  for (int mi = 0; mi < 2; mi++)
    pA[mi] = query + (size_t)(m0 + mi * 16 + l16) * 512 + quad * 8;

  for (int bb = bFirst; bb <= bLast; bb++) {
    // ---- phase 1: scores = q x Kq[bb]^T, fragments direct from global ----
    const u16* Bq = Kqb + (size_t)bb * 65536;
    const u16* pB[2];
#pragma unroll
    for (int ni = 0; ni < 2; ni++)
      pB[ni] = Bq + (size_t)(wc + ni * 16 + l16) * 512 + quad * 8;

    f32x4 acc1[2][2];
#pragma unroll
    for (int i = 0; i < 2; i++)
#pragma unroll
      for (int j = 0; j < 2; j++) acc1[i][j] = (f32x4){0.f, 0.f, 0.f, 0.f};

#pragma unroll 4
    for (int t = 0; t < 16; t++) {
      short8 af[2], bfr[2];
#pragma unroll
      for (int mi = 0; mi < 2; mi++) {
        float4 a0 = *(const float4*)(pA[mi] + t * 32);
        float4 a1 = *(const float4*)(pA[mi] + t * 32 + 4);
        short8 v;
        v[0] = (short)f2bf(a0.x); v[1] = (short)f2bf(a0.y);
        v[2] = (short)f2bf(a0.z); v[3] = (short)f2bf(a0.w);
        v[4] = (short)f2bf(a1.x); v[5] = (short)f2bf(a1.y);
        v[6] = (short)f2bf(a1.z); v[7] = (short)f2bf(a1.w);
        af[mi] = v;
      }
#pragma unroll
      for (int ni = 0; ni < 2; ni++) bfr[ni] = *(const short8*)(pB[ni] + t * 32);
#pragma unroll
      for (int mi = 0; mi < 2; mi++)
#pragma unroll
        for (int ni = 0; ni < 2; ni++)
          acc1[mi][ni] = __builtin_amdgcn_mfma_f32_16x16x32_bf16(af[mi], bfr[ni], acc1[mi][ni], 0, 0, 0);
    }

    // ---- softmax over each head's 16 l-cols (16-lane shfl), P -> LDS ----
    float sbv[2];
#pragma unroll
    for (int ni = 0; ni < 2; ni++) sbv[ni] = sb[bb * 128 + wc + ni * 16 + l16];
#pragma unroll
    for (int mi = 0; mi < 2; mi++) {
#pragma unroll
      for (int r = 0; r < 4; r++) {
        const int row = mi * 16 + quad * 4 + r;   // 0..31
#pragma unroll
        for (int ni = 0; ni < 2; ni++) {
          float v = acc1[mi][ni][r] + sbv[ni];
          float mx = v;
          mx = fmaxf(mx, __shfl_xor(mx, 1));
          mx = fmaxf(mx, __shfl_xor(mx, 2));
          mx = fmaxf(mx, __shfl_xor(mx, 4));
          mx = fmaxf(mx, __shfl_xor(mx, 8));
          float ev = __expf((v - mx) * 0.125f);   // scale = D^-0.5
          float s = ev;
          s += __shfl_xor(s, 1);
          s += __shfl_xor(s, 2);
          s += __shfl_xor(s, 4);
          s += __shfl_xor(s, 8);
          const int col = wc + ni * 16 + l16;
          Ps[row * 128 + (((col >> 3) ^ (row & 7)) << 3) + (col & 7)] = f2bf(ev / s);
        }
      }
    }
    __syncthreads();   // all P stripes visible

    // ---- phase 2: out[32,512] = P x WoV[bb]^T; wave owns 128 f-cols ----
    const u16* Wv = WoVb + (size_t)bb * 65536;
#pragma unroll
    for (int h2 = 0; h2 < 2; h2++) {
      const int f0 = wave * 128 + h2 * 64;
      f32x4 acc2[2][4];
#pragma unroll
      for (int i = 0; i < 2; i++)
#pragma unroll
        for (int j = 0; j < 4; j++) acc2[i][j] = (f32x4){0.f, 0.f, 0.f, 0.f};
#pragma unroll
      for (int kk = 0; kk < 4; kk++) {
        short8 paf[2], bf2[4];
#pragma unroll
        for (int mi = 0; mi < 2; mi++) {
          const int row = mi * 16 + l16;
          paf[mi] = *(const short8*)&Ps[row * 128 + (((kk * 4 + quad) ^ (row & 7)) << 3)];
        }
#pragma unroll
        for (int ni = 0; ni < 4; ni++) {
          const int fr = f0 + ni * 16 + l16;
          bf2[ni] = *(const short8*)(Wv + (size_t)fr * 128 + kk * 32 + quad * 8);
        }
#pragma unroll
        for (int mi = 0; mi < 2; mi++)
#pragma unroll
          for (int ni = 0; ni < 4; ni++)
            acc2[mi][ni] = __builtin_amdgcn_mfma_f32_16x16x32_bf16(paf[mi], bf2[ni], acc2[mi][ni], 0, 0, 0);
      }
      float bov[4];
#pragma unroll
      for (int ni = 0; ni < 4; ni++) bov[ni] = bo[f0 + ni * 16 + l16];
#pragma unroll
      for (int mi = 0; mi < 2; mi++)
#pragma unroll
        for (int r = 0; r < 4; r++) {
          if (rowb[mi][r] == bb) {
            const size_t row = m0 + mi * 16 + quad * 4 + r;
#pragma unroll
            for (int ni = 0; ni < 4; ni++)
              __builtin_nontemporal_store(acc2[mi][ni][r] + bov[ni],
                                          &out[row * 512 + f0 + ni * 16 + l16]);
          }
        }
    }
    __syncthreads();   // protect Ps before next bb overwrites
  }
}

extern "C" void kernel_launch(void* const* d_in, const int* in_sizes, int n_in,
                              void* d_out, int out_size, void* d_ws, size_t ws_size,
                              hipStream_t stream) {
  const float* query = (const float*)d_in[0];
  const float* keyt = (const float*)d_in[1];
  const float* valt = (const float*)d_in[2];
  const int* bidx = (const int*)d_in[3];
  // d_in[4] = batch_size (scalar, fixed = 8)
  const float* Wq = (const float*)d_in[5];
  const float* bq = (const float*)d_in[6];
  const float* Wk = (const float*)d_in[7];
  const float* bk = (const float*)d_in[8];
  const float* Wv = (const float*)d_in[9];
  const float* bv = (const float*)d_in[10];
  const float* Wo = (const float*)d_in[11];
  const float* bo = (const float*)d_in[12];
  float* out = (float*)d_out;

  // workspace layout (bytes)
  unsigned char* w = (unsigned char*)d_ws;
  float* kproj = (float*)(w + 41943040ull);   //    262,144: [B,H,D,L]
  float* vproj = (float*)(w + 42205184ull);   //    262,144: [B,H,L,D]
  u16* Kqb = (u16*)(w + 42467328ull);         //  1,048,576: [B,128,512] bf16
  u16* WoVb = (u16*)(w + 43515904ull);        //  1,048,576: [B,512,128] bf16
  float* sb = (float*)(w + 44564480ull);      //      4,096: [B,128]

  // 1) K/V projections (fp32, tiny)
  kvproj_kernel<<<512, 256, 0, stream>>>(keyt, valt, Wk, bk, Wv, bv, kproj, vproj);

  // 2) fold Wq through k, Wo through v
  build_kq<<<2048, 256, 0, stream>>>(kproj, Wq, Kqb);
  build_sb<<<4, 256, 0, stream>>>(kproj, bq, sb);
  build_wov<<<2048, 256, 0, stream>>>(vproj, Wo, WoVb);

  // 3) fused: fp32 query -> scores -> softmax -> out (cvt folded in)
  fused_attn<<<N_TOKENS / 32, 256, 0, stream>>>(query, Kqb, WoVb, sb, bo, bidx, out);
}